// Round 6
// baseline (827.390 us; speedup 1.0000x reference)
//
#include <hip/hip_runtime.h>
#include <math.h>

#define N_USERS 50000
#define N_ITEMS 100000
#define N_ENT   200000
#define N_NODES (N_USERS + N_ITEMS)
#define N_REL   32
#define DIM     64

#define NB_KG  391          // KG buckets: dst>>9 (512 keys each)
#define NB_UI  586          // UI buckets: row>>8 (256 keys each)
#define NB_TOT (NB_KG + NB_UI)   // 977
#define CAPD   8192         // max edges per bucket in finalize LDS

// ---------------------------------------------------------------------------
// y[r][j] = sum_k x[r][k] * w[j][k]. Lane j holds w[j][*] in 64 VGPRs.
// 8 rows per wave-iteration -> 8 independent FMA chains (latency hiding).
// ---------------------------------------------------------------------------
__global__ __launch_bounds__(256) void ent_matmul(const float* __restrict__ x,
                                                  const float* __restrict__ w,
                                                  float* __restrict__ y, int n_ent) {
    int lane = threadIdx.x & 63;
    float wr[64];
    #pragma unroll
    for (int k4 = 0; k4 < 16; k4++) {
        float4 v = ((const float4*)w)[lane * 16 + k4];
        wr[k4 * 4 + 0] = v.x; wr[k4 * 4 + 1] = v.y;
        wr[k4 * 4 + 2] = v.z; wr[k4 * 4 + 3] = v.w;
    }
    int wave = (blockIdx.x * blockDim.x + threadIdx.x) >> 6;
    int nw   = (gridDim.x * blockDim.x) >> 6;
    for (int base = wave * 8; base < n_ent; base += nw * 8) {
        float xv[8], acc[8];
        #pragma unroll
        for (int r = 0; r < 8; r++) {
            int rr = base + r;
            xv[r]  = (rr < n_ent) ? x[(long)rr * 64 + lane] : 0.f;
            acc[r] = 0.f;
        }
        #pragma unroll
        for (int k = 0; k < 64; k++) {
            float wk = wr[k];
            #pragma unroll
            for (int r = 0; r < 8; r++)
                acc[r] += __shfl(xv[r], k) * wk;
        }
        #pragma unroll
        for (int r = 0; r < 8; r++) {
            int rr = base + r;
            if (rr < n_ent) y[(long)rr * 64 + lane] = acc[r];
        }
    }
}

// ---------------------------------------------------------------------------
// Pass A: per-block LDS bucket histogram, one global atomic per (block,bucket)
// ---------------------------------------------------------------------------
__global__ __launch_bounds__(256) void bucket_hist(const int* __restrict__ kg_dst,
                                                   const int* __restrict__ ui_row,
                                                   int* __restrict__ bcnt,
                                                   int e_kg, int e_ui) {
    __shared__ int h[NB_TOT];
    for (int i = threadIdx.x; i < NB_TOT; i += 256) h[i] = 0;
    __syncthreads();
    int n = e_kg + e_ui;
    int t = blockIdx.x * 256 + threadIdx.x;
    int stride = gridDim.x * 256;
    for (int e = t; e < n; e += stride) {
        int bk = (e < e_kg) ? (kg_dst[e] >> 9) : (NB_KG + (ui_row[e - e_kg] >> 8));
        atomicAdd(&h[bk], 1);
    }
    __syncthreads();
    for (int i = threadIdx.x; i < NB_TOT; i += 256)
        if (h[i]) atomicAdd(&bcnt[i], h[i]);
}

// ---------------------------------------------------------------------------
// Pass B: exclusive scan of bucket counts, per segment (kg, ui). 1 block.
// ---------------------------------------------------------------------------
__global__ __launch_bounds__(256) void bucket_scan(const int* __restrict__ bcnt,
                                                   int* __restrict__ boff_kg,
                                                   int* __restrict__ boff_ui,
                                                   int* __restrict__ bcur,
                                                   int e_kg, int e_ui) {
    __shared__ int sh[1024];
    int t = threadIdx.x;
    for (int seg = 0; seg < 2; seg++) {
        int NB = seg ? NB_UI : NB_KG;
        const int* src = bcnt + (seg ? NB_KG : 0);
        int idx[4] = { t, t + 256, t + 512, t + 768 };
        int v[4];
        #pragma unroll
        for (int q = 0; q < 4; q++) {
            v[q] = (idx[q] < NB) ? src[idx[q]] : 0;
            sh[idx[q]] = v[q];
        }
        __syncthreads();
        for (int o = 1; o < 1024; o <<= 1) {
            int a[4];
            #pragma unroll
            for (int q = 0; q < 4; q++) a[q] = (idx[q] >= o) ? sh[idx[q] - o] : 0;
            __syncthreads();
            #pragma unroll
            for (int q = 0; q < 4; q++) sh[idx[q]] += a[q];
            __syncthreads();
        }
        int* boff = seg ? boff_ui : boff_kg;
        int  base = seg ? NB_KG : 0;
        #pragma unroll
        for (int q = 0; q < 4; q++) {
            if (idx[q] < NB) {
                int ex = sh[idx[q]] - v[q];
                boff[idx[q]] = ex;
                bcur[base + idx[q]] = ex;
            }
        }
        if (t == 0) boff[NB] = seg ? e_ui : e_kg;
        __syncthreads();
    }
}

// ---------------------------------------------------------------------------
// Pass C: scatter edges into bucket regions.
// KG rec: src(18) | rel<<18 (5) | dst_local<<23 (9)
// UI rec: col(18) | row_local<<18 (8)
// ---------------------------------------------------------------------------
__global__ __launch_bounds__(256) void bucket_scatter(const int* __restrict__ kg_src,
                                                      const int* __restrict__ kg_dst,
                                                      const int* __restrict__ kg_rel,
                                                      const int* __restrict__ ui_row,
                                                      const int* __restrict__ ui_col,
                                                      int* __restrict__ bcur,
                                                      unsigned int* __restrict__ kgrec,
                                                      int* __restrict__ uirec,
                                                      int e_kg, int e_ui) {
    __shared__ int h[NB_TOT];
    __shared__ int lbase[NB_TOT];
    int n = e_kg + e_ui;
    int nchunks = (n + 4095) >> 12;
    int tid = threadIdx.x;
    for (int c = blockIdx.x; c < nchunks; c += gridDim.x) {
        int base = c << 12;
        for (int i = tid; i < NB_TOT; i += 256) h[i] = 0;
        __syncthreads();
        unsigned int rec[16];
        int bk[16];
        #pragma unroll
        for (int j = 0; j < 16; j++) {
            int e = base + j * 256 + tid;
            if (e < n) {
                if (e < e_kg) {
                    int d = kg_dst[e];
                    bk[j]  = d >> 9;
                    rec[j] = (unsigned int)kg_src[e] | ((unsigned int)kg_rel[e] << 18)
                             | ((unsigned int)(d & 511) << 23);
                } else {
                    int i2 = e - e_kg;
                    int r  = ui_row[i2];
                    bk[j]  = NB_KG + (r >> 8);
                    rec[j] = (unsigned int)ui_col[i2] | ((unsigned int)(r & 255) << 18);
                }
                atomicAdd(&h[bk[j]], 1);
            } else bk[j] = -1;
        }
        __syncthreads();
        for (int i = tid; i < NB_TOT; i += 256) {
            int cc = h[i];
            lbase[i] = cc ? atomicAdd(&bcur[i], cc) : 0;
        }
        __syncthreads();
        #pragma unroll
        for (int j = 0; j < 16; j++) {
            if (bk[j] >= 0) {
                int pos = atomicAdd(&lbase[bk[j]], 1);
                if (bk[j] < NB_KG) kgrec[pos] = rec[j];
                else               uirec[pos] = (int)rec[j];
            }
        }
        __syncthreads();
    }
}

// ---------------------------------------------------------------------------
// Pass D: one block per bucket. LDS counting-sort by local key; emits CSR
// off[], sorted records, and (UI) dinv[].
// ---------------------------------------------------------------------------
__global__ __launch_bounds__(256) void bucket_finalize(const int* __restrict__ boff_kg,
                                                       const int* __restrict__ boff_ui,
                                                       unsigned int* __restrict__ kgrec,
                                                       int* __restrict__ uirec,
                                                       int* __restrict__ off_kg,
                                                       int* __restrict__ off_ui,
                                                       float* __restrict__ dinv,
                                                       int e_kg, int e_ui) {
    __shared__ unsigned int rec[CAPD];
    __shared__ int hist[512];
    bool iskg = blockIdx.x < NB_KG;
    int  b    = iskg ? blockIdx.x : blockIdx.x - NB_KG;
    const int* boff = iskg ? boff_kg : boff_ui;
    int ebeg = boff[b], eend = boff[b + 1];
    int ne   = min(eend - ebeg, CAPD);
    int key_base = iskg ? (b << 9) : (b << 8);
    int nkeys = iskg ? min(512, N_ENT - key_base) : min(256, N_NODES - key_base);
    int SH = iskg ? 23 : 18;
    int tid = threadIdx.x;

    for (int i = tid; i < ne; i += 256)
        rec[i] = iskg ? kgrec[ebeg + i] : (unsigned int)uirec[ebeg + i];
    for (int i = tid; i < 512; i += 256) hist[i] = 0;
    __syncthreads();
    for (int i = tid; i < ne; i += 256)
        atomicAdd(&hist[rec[i] >> SH], 1);
    __syncthreads();
    if (!iskg) {
        for (int i = tid; i < nkeys; i += 256) {
            int d = hist[i];
            dinv[key_base + i] = d > 0 ? 1.0f / sqrtf((float)d) : 0.0f;
        }
    }
    int i0 = tid, i1 = tid + 256;
    int v0 = hist[i0], v1 = hist[i1];
    __syncthreads();
    for (int o = 1; o < 512; o <<= 1) {
        int a0 = (i0 >= o) ? hist[i0 - o] : 0;
        int a1 = (i1 >= o) ? hist[i1 - o] : 0;
        __syncthreads();
        hist[i0] += a0; hist[i1] += a1;
        __syncthreads();
    }
    int e0 = hist[i0] - v0, e1 = hist[i1] - v1;
    __syncthreads();
    hist[i0] = e0; hist[i1] = e1;
    int* offg = iskg ? off_kg : off_ui;
    if (i0 < nkeys) offg[key_base + i0] = ebeg + e0;
    if (i1 < nkeys) offg[key_base + i1] = ebeg + e1;
    if (blockIdx.x == 0 && tid == 0) {
        off_kg[N_ENT]   = e_kg;
        off_ui[N_NODES] = e_ui;
    }
    __syncthreads();
    for (int i = tid; i < ne; i += 256) {
        unsigned int r = rec[i];
        int k = r >> SH;
        int slot = atomicAdd(&hist[k], 1);
        if (iskg) kgrec[ebeg + slot] = r & 0x7FFFFFu;
        else      uirec[ebeg + slot] = (int)(r & 0x3FFFFu);
    }
}

// ---------------------------------------------------------------------------
// kg_aggregate: one wave per entity row, 8x unrolled edge loop (8 gathers
// in flight per wave).
// ---------------------------------------------------------------------------
__global__ void kg_aggregate(const int* __restrict__ off, const unsigned int* __restrict__ packed,
                             const float* __restrict__ y, const float* __restrict__ x0,
                             const float* __restrict__ rel_emb, float* __restrict__ xkg,
                             int n_ent) {
    __shared__ float gate[N_REL * 64];
    for (int idx = threadIdx.x; idx < N_REL * 64; idx += blockDim.x)
        gate[idx] = 1.0f / (1.0f + __expf(-rel_emb[idx]));
    __syncthreads();
    int lane = threadIdx.x & 63;
    int wave = (blockIdx.x * blockDim.x + threadIdx.x) >> 6;
    int nw   = (gridDim.x * blockDim.x) >> 6;
    for (int r = wave; r < n_ent; r += nw) {
        int beg = off[r], end = off[r + 1];
        float acc[8];
        #pragma unroll
        for (int q = 0; q < 8; q++) acc[q] = 0.f;
        int p = beg;
        for (; p + 8 <= end; p += 8) {
            unsigned int pk[8];
            #pragma unroll
            for (int q = 0; q < 8; q++) pk[q] = packed[p + q];
            float v[8];
            #pragma unroll
            for (int q = 0; q < 8; q++)
                v[q] = y[(long)(pk[q] & 0x3FFFF) * 64 + lane];
            #pragma unroll
            for (int q = 0; q < 8; q++)
                acc[q] += v[q] * gate[(pk[q] >> 18) * 64 + lane];
        }
        for (; p < end; p++) {
            unsigned int pk = packed[p];
            acc[0] += y[(long)(pk & 0x3FFFF) * 64 + lane] * gate[(pk >> 18) * 64 + lane];
        }
        float a = ((acc[0] + acc[1]) + (acc[2] + acc[3]))
                + ((acc[4] + acc[5]) + (acc[6] + acc[7]));
        float deg = fmaxf((float)(end - beg), 1.0f);
        float v = a / deg + x0[(long)r * 64 + lane];
        v = (v > 0.0f) ? v : (__expf(v) - 1.0f);      // elu, alpha=1
        float ss = v * v;
        #pragma unroll
        for (int o = 32; o; o >>= 1) ss += __shfl_xor(ss, o);
        xkg[(long)r * 64 + lane] = v / fmaxf(sqrtf(ss), 1e-12f);
    }
}

// ---------------------------------------------------------------------------
// build_all: all_emb = [user_emb ; xkg[i2e]]
// ---------------------------------------------------------------------------
__global__ void build_all(const float* __restrict__ user_emb, const float* __restrict__ xkg,
                          const int* __restrict__ i2e, float* __restrict__ all_emb) {
    int lane = threadIdx.x & 63;
    int wave = (blockIdx.x * blockDim.x + threadIdx.x) >> 6;
    int nw   = (gridDim.x * blockDim.x) >> 6;
    for (int r = wave; r < N_NODES; r += nw) {
        float v;
        if (r < N_USERS) {
            v = user_emb[(long)r * 64 + lane];
        } else {
            long ent = i2e[r - N_USERS];
            v = xkg[ent * 64 + lane];
        }
        all_emb[(long)r * 64 + lane] = v;
    }
}

// ---------------------------------------------------------------------------
// ui_aggregate: val = dinv[r]*dinv[c]; 8x unrolled gather loop.
// final = 0.5*(all_emb[r] + dinv[r]*sum(dinv[c]*all_emb[c]))
// ---------------------------------------------------------------------------
__global__ void ui_aggregate(const int* __restrict__ off, const int* __restrict__ colrec,
                             const float* __restrict__ all_emb, const float* __restrict__ dinv,
                             float* __restrict__ final_emb) {
    int lane = threadIdx.x & 63;
    int wave = (blockIdx.x * blockDim.x + threadIdx.x) >> 6;
    int nw   = (gridDim.x * blockDim.x) >> 6;
    for (int r = wave; r < N_NODES; r += nw) {
        int beg = off[r], end = off[r + 1];
        float acc[8];
        #pragma unroll
        for (int q = 0; q < 8; q++) acc[q] = 0.f;
        int p = beg;
        for (; p + 8 <= end; p += 8) {
            int c[8];
            #pragma unroll
            for (int q = 0; q < 8; q++) c[q] = colrec[p + q];
            float dv[8], v[8];
            #pragma unroll
            for (int q = 0; q < 8; q++) dv[q] = dinv[c[q]];
            #pragma unroll
            for (int q = 0; q < 8; q++) v[q] = all_emb[(long)c[q] * 64 + lane];
            #pragma unroll
            for (int q = 0; q < 8; q++) acc[q] += dv[q] * v[q];
        }
        for (; p < end; p++) {
            int c = colrec[p];
            acc[0] += dinv[c] * all_emb[(long)c * 64 + lane];
        }
        float a = (((acc[0] + acc[1]) + (acc[2] + acc[3]))
                 + ((acc[4] + acc[5]) + (acc[6] + acc[7]))) * dinv[r];
        final_emb[(long)r * 64 + lane] =
            0.5f * (all_emb[(long)r * 64 + lane] + a);
    }
}

// ---------------------------------------------------------------------------
// Epilogue (intent folded in): one wave per sample.
// ---------------------------------------------------------------------------
__global__ void final_kernel(const int* __restrict__ u, const int* __restrict__ ipos,
                             const int* __restrict__ ineg,
                             const float* __restrict__ final_emb,
                             const float* __restrict__ all_emb,
                             const float* __restrict__ rw, const float* __restrict__ rb,
                             const float* __restrict__ iw, const float* __restrict__ rel_emb,
                             float* __restrict__ out, int B) {
    __shared__ float sh_intent[128];
    if (threadIdx.x < 64) {
        int j = threadIdx.x;
        for (int k = 0; k < 2; k++) {
            float m = -1e30f;
            for (int r = 0; r < N_REL; r++) m = fmaxf(m, iw[k * N_REL + r]);
            float Z = 0.f, acc = 0.f;
            for (int r = 0; r < N_REL; r++) {
                float e = __expf(iw[k * N_REL + r] - m);
                Z += e;
                acc += e * rel_emb[r * 64 + j];
            }
            sh_intent[k * 64 + j] = acc / Z;
        }
    }
    __syncthreads();
    int lane = threadIdx.x & 63;
    int wave = (blockIdx.x * blockDim.x + threadIdx.x) >> 6;
    int nw   = (gridDim.x * blockDim.x) >> 6;
    for (int b = wave; b < B; b += nw) {
        int uu = u[b];
        float up = final_emb[(long)uu * 64 + lane];
        float l0 = up * rw[lane];
        float l1 = up * rw[64 + lane];
        #pragma unroll
        for (int o = 32; o; o >>= 1) {
            l0 += __shfl_xor(l0, o);
            l1 += __shfl_xor(l1, o);
        }
        l0 += rb[0]; l1 += rb[1];
        float m  = fmaxf(l0, l1);
        float e0 = __expf(l0 - m), e1 = __expf(l1 - m);
        float inv = 1.0f / (e0 + e1);
        float p0 = e0 * inv, p1 = e1 * inv;
        float ue = up + p0 * sh_intent[lane] + p1 * sh_intent[64 + lane];

        int it = ipos[b];
        long rr = (long)(N_USERS + it) * 64 + lane;
        float ie = final_emb[rr] + all_emb[rr];
        float dp = ue * ie;
        #pragma unroll
        for (int o = 32; o; o >>= 1) dp += __shfl_xor(dp, o);
        if (lane == 0) out[b] = dp;

        it = ineg[b];
        rr = (long)(N_USERS + it) * 64 + lane;
        ie = final_emb[rr] + all_emb[rr];
        dp = ue * ie;
        #pragma unroll
        for (int o = 32; o; o >>= 1) dp += __shfl_xor(dp, o);
        if (lane == 0) out[B + b] = dp;
    }
}

extern "C" void kernel_launch(void* const* d_in, const int* in_sizes, int n_in,
                              void* d_out, int out_size, void* d_ws, size_t ws_size,
                              hipStream_t stream) {
    const int*   u          = (const int*)  d_in[0];
    const int*   ipos       = (const int*)  d_in[1];
    const int*   ineg       = (const int*)  d_in[2];
    const float* user_emb   = (const float*)d_in[3];
    const float* entity_emb = (const float*)d_in[4];
    const float* rel_emb    = (const float*)d_in[5];
    const float* iw         = (const float*)d_in[6];
    const float* rw         = (const float*)d_in[7];
    const float* rb         = (const float*)d_in[8];
    const float* kgw        = (const float*)d_in[9];
    const int*   i2e        = (const int*)  d_in[11];
    const int*   kg_src     = (const int*)  d_in[12];
    const int*   kg_dst     = (const int*)  d_in[13];
    const int*   kg_rel     = (const int*)  d_in[14];
    const int*   ui_row     = (const int*)  d_in[15];
    const int*   ui_col     = (const int*)  d_in[16];
    float*       out        = (float*)d_out;

    int B    = in_sizes[0];
    int e_kg = in_sizes[12];
    int e_ui = in_sizes[15];

    // ---------------- workspace layout (bytes) ----------------
    char* ws = (char*)d_ws;
    float*        y          = (float*)(ws + 0);            // 51.2 MB, reused as all_emb
    float*        all_emb    = (float*)(ws + 0);
    float*        xkg        = (float*)(ws + 51200000);     // 51.2 MB, reused as final_emb
    float*        final_emb  = (float*)(ws + 51200000);
    unsigned int* kgrec      = (unsigned int*)(ws + 102400000); // 8 MB (2M recs)
    int*          uirec      = (int*)(ws + 110400000);      // 8 MB (2M recs)
    int*          off_kg     = (int*)(ws + 118400000);      // 200001 ints
    int*          off_ui     = (int*)(ws + 119200256);      // 150001 ints
    float*        dinv       = (float*)(ws + 119800512);    // 150000 floats
    int*          bcnt       = (int*)(ws + 120400512);      // 977 ints
    int*          boff_kg    = (int*)(ws + 120404480);      // 392 ints
    int*          boff_ui    = (int*)(ws + 120406272);      // 587 ints
    int*          bcur       = (int*)(ws + 120408704);      // 977 ints

    hipMemsetAsync(bcnt, 0, NB_TOT * sizeof(int), stream);
    bucket_hist    <<<256, 256, 0, stream>>>(kg_dst, ui_row, bcnt, e_kg, e_ui);
    bucket_scan    <<<1,   256, 0, stream>>>(bcnt, boff_kg, boff_ui, bcur, e_kg, e_ui);
    bucket_scatter <<<512, 256, 0, stream>>>(kg_src, kg_dst, kg_rel, ui_row, ui_col,
                                             bcur, kgrec, uirec, e_kg, e_ui);
    bucket_finalize<<<NB_TOT, 256, 0, stream>>>(boff_kg, boff_ui, kgrec, uirec,
                                                off_kg, off_ui, dinv, e_kg, e_ui);

    ent_matmul  <<<2048, 256, 0, stream>>>(entity_emb, kgw, y, N_ENT);
    kg_aggregate<<<4096, 256, 0, stream>>>(off_kg, kgrec, y, entity_emb, rel_emb, xkg, N_ENT);
    build_all   <<<2048, 256, 0, stream>>>(user_emb, xkg, i2e, all_emb);
    ui_aggregate<<<4096, 256, 0, stream>>>(off_ui, uirec, all_emb, dinv, final_emb);
    final_kernel<<<256,  256, 0, stream>>>(u, ipos, ineg, final_emb, all_emb,
                                           rw, rb, iw, rel_emb, out, B);
}

// Round 7
// 534.717 us; speedup vs baseline: 1.5473x; 1.5473x over previous
//
#include <hip/hip_runtime.h>
#include <math.h>

#define N_USERS 50000
#define N_ITEMS 100000
#define N_ENT   200000
#define N_NODES (N_USERS + N_ITEMS)
#define N_REL   32
#define DIM     64

#define NB_KG  391          // KG buckets: dst>>9 (512 keys each)
#define NB_UI  586          // UI buckets: row>>8 (256 keys each)
#define NB_TOT (NB_KG + NB_UI)   // 977
#define CAPD   8192         // max edges per bucket in finalize LDS

// ---------------------------------------------------------------------------
// ent_matmul: y = x @ W^T as register-tiled LDS GEMM.
// 128 rows/block, 128 threads, 8x8 C-tile per thread. No shuffles (CDNA
// __shfl = ds_bpermute -> LDS-pipe bound; R5/R6 lesson). LDS rows padded to
// multiples of 4 floats so ds_read_b128 alignment holds; stride%32==4 keeps
// banks conflict-free for the 8-strided tile reads.
// ---------------------------------------------------------------------------
__global__ __launch_bounds__(128) void ent_matmul(const float* __restrict__ x,
                                                  const float* __restrict__ w,
                                                  float* __restrict__ y, int n_ent) {
    __shared__ float xt[64][132];   // xt[k][r], 33,792 B
    __shared__ float wt[64][68];    // wt[k][j], 17,408 B
    int tid  = threadIdx.x;
    int base = blockIdx.x * 128;

    // stage W^T: w[j][k] -> wt[k][j]
    #pragma unroll
    for (int q = 0; q < 8; q++) {
        int idx = q * 128 + tid;          // 1024 float4s
        int j = idx >> 4, k4 = idx & 15;
        float4 v = ((const float4*)w)[idx];
        wt[4 * k4 + 0][j] = v.x;
        wt[4 * k4 + 1][j] = v.y;
        wt[4 * k4 + 2][j] = v.z;
        wt[4 * k4 + 3][j] = v.w;
    }
    // stage x^T: x[gr][k] -> xt[k][r]  (coalesced float4 reads)
    #pragma unroll
    for (int q = 0; q < 16; q++) {
        int idx = q * 128 + tid;          // 2048 float4s
        int r = idx >> 4, k4 = idx & 15;
        int gr = base + r;
        if (gr < n_ent) {
            float4 v = ((const float4*)x)[(long)gr * 16 + k4];
            xt[4 * k4 + 0][r] = v.x;
            xt[4 * k4 + 1][r] = v.y;
            xt[4 * k4 + 2][r] = v.z;
            xt[4 * k4 + 3][r] = v.w;
        }
    }
    __syncthreads();

    int j0 = (tid & 7) * 8;
    int r0 = (tid >> 3) * 8;
    float acc[8][8];
    #pragma unroll
    for (int i = 0; i < 8; i++)
        #pragma unroll
        for (int j = 0; j < 8; j++) acc[i][j] = 0.f;

    #pragma unroll 4
    for (int k = 0; k < 64; k++) {
        float4 xa = *(const float4*)&xt[k][r0];
        float4 xb = *(const float4*)&xt[k][r0 + 4];
        float4 wa = *(const float4*)&wt[k][j0];
        float4 wb = *(const float4*)&wt[k][j0 + 4];
        float xr[8] = {xa.x, xa.y, xa.z, xa.w, xb.x, xb.y, xb.z, xb.w};
        float wr[8] = {wa.x, wa.y, wa.z, wa.w, wb.x, wb.y, wb.z, wb.w};
        #pragma unroll
        for (int i = 0; i < 8; i++)
            #pragma unroll
            for (int j = 0; j < 8; j++)
                acc[i][j] += xr[i] * wr[j];
    }

    #pragma unroll
    for (int i = 0; i < 8; i++) {
        int gr = base + r0 + i;
        if (gr < n_ent) {
            float4 o0 = {acc[i][0], acc[i][1], acc[i][2], acc[i][3]};
            float4 o1 = {acc[i][4], acc[i][5], acc[i][6], acc[i][7]};
            *(float4*)&y[(long)gr * 64 + j0]     = o0;
            *(float4*)&y[(long)gr * 64 + j0 + 4] = o1;
        }
    }
}

// ---------------------------------------------------------------------------
// Pass A: per-block LDS bucket histogram, one global atomic per (block,bucket)
// ---------------------------------------------------------------------------
__global__ __launch_bounds__(256) void bucket_hist(const int* __restrict__ kg_dst,
                                                   const int* __restrict__ ui_row,
                                                   int* __restrict__ bcnt,
                                                   int e_kg, int e_ui) {
    __shared__ int h[NB_TOT];
    for (int i = threadIdx.x; i < NB_TOT; i += 256) h[i] = 0;
    __syncthreads();
    int n = e_kg + e_ui;
    int t = blockIdx.x * 256 + threadIdx.x;
    int stride = gridDim.x * 256;
    for (int e = t; e < n; e += stride) {
        int bk = (e < e_kg) ? (kg_dst[e] >> 9) : (NB_KG + (ui_row[e - e_kg] >> 8));
        atomicAdd(&h[bk], 1);
    }
    __syncthreads();
    for (int i = threadIdx.x; i < NB_TOT; i += 256)
        if (h[i]) atomicAdd(&bcnt[i], h[i]);
}

// ---------------------------------------------------------------------------
// Pass B: exclusive scan of bucket counts, per segment (kg, ui). 1 block.
// ---------------------------------------------------------------------------
__global__ __launch_bounds__(256) void bucket_scan(const int* __restrict__ bcnt,
                                                   int* __restrict__ boff_kg,
                                                   int* __restrict__ boff_ui,
                                                   int* __restrict__ bcur,
                                                   int e_kg, int e_ui) {
    __shared__ int sh[1024];
    int t = threadIdx.x;
    for (int seg = 0; seg < 2; seg++) {
        int NB = seg ? NB_UI : NB_KG;
        const int* src = bcnt + (seg ? NB_KG : 0);
        int idx[4] = { t, t + 256, t + 512, t + 768 };
        int v[4];
        #pragma unroll
        for (int q = 0; q < 4; q++) {
            v[q] = (idx[q] < NB) ? src[idx[q]] : 0;
            sh[idx[q]] = v[q];
        }
        __syncthreads();
        for (int o = 1; o < 1024; o <<= 1) {
            int a[4];
            #pragma unroll
            for (int q = 0; q < 4; q++) a[q] = (idx[q] >= o) ? sh[idx[q] - o] : 0;
            __syncthreads();
            #pragma unroll
            for (int q = 0; q < 4; q++) sh[idx[q]] += a[q];
            __syncthreads();
        }
        int* boff = seg ? boff_ui : boff_kg;
        int  base = seg ? NB_KG : 0;
        #pragma unroll
        for (int q = 0; q < 4; q++) {
            if (idx[q] < NB) {
                int ex = sh[idx[q]] - v[q];
                boff[idx[q]] = ex;
                bcur[base + idx[q]] = ex;
            }
        }
        if (t == 0) boff[NB] = seg ? e_ui : e_kg;
        __syncthreads();
    }
}

// ---------------------------------------------------------------------------
// Pass C: scatter edges into bucket regions.
// KG rec: src(18) | rel<<18 (5) | dst_local<<23 (9)
// UI rec: col(18) | row_local<<18 (8)
// ---------------------------------------------------------------------------
__global__ __launch_bounds__(256) void bucket_scatter(const int* __restrict__ kg_src,
                                                      const int* __restrict__ kg_dst,
                                                      const int* __restrict__ kg_rel,
                                                      const int* __restrict__ ui_row,
                                                      const int* __restrict__ ui_col,
                                                      int* __restrict__ bcur,
                                                      unsigned int* __restrict__ kgrec,
                                                      int* __restrict__ uirec,
                                                      int e_kg, int e_ui) {
    __shared__ int h[NB_TOT];
    __shared__ int lbase[NB_TOT];
    int n = e_kg + e_ui;
    int nchunks = (n + 4095) >> 12;
    int tid = threadIdx.x;
    for (int c = blockIdx.x; c < nchunks; c += gridDim.x) {
        int base = c << 12;
        for (int i = tid; i < NB_TOT; i += 256) h[i] = 0;
        __syncthreads();
        unsigned int rec[16];
        int bk[16];
        #pragma unroll
        for (int j = 0; j < 16; j++) {
            int e = base + j * 256 + tid;
            if (e < n) {
                if (e < e_kg) {
                    int d = kg_dst[e];
                    bk[j]  = d >> 9;
                    rec[j] = (unsigned int)kg_src[e] | ((unsigned int)kg_rel[e] << 18)
                             | ((unsigned int)(d & 511) << 23);
                } else {
                    int i2 = e - e_kg;
                    int r  = ui_row[i2];
                    bk[j]  = NB_KG + (r >> 8);
                    rec[j] = (unsigned int)ui_col[i2] | ((unsigned int)(r & 255) << 18);
                }
                atomicAdd(&h[bk[j]], 1);
            } else bk[j] = -1;
        }
        __syncthreads();
        for (int i = tid; i < NB_TOT; i += 256) {
            int cc = h[i];
            lbase[i] = cc ? atomicAdd(&bcur[i], cc) : 0;
        }
        __syncthreads();
        #pragma unroll
        for (int j = 0; j < 16; j++) {
            if (bk[j] >= 0) {
                int pos = atomicAdd(&lbase[bk[j]], 1);
                if (bk[j] < NB_KG) kgrec[pos] = rec[j];
                else               uirec[pos] = (int)rec[j];
            }
        }
        __syncthreads();
    }
}

// ---------------------------------------------------------------------------
// Pass D: one block per bucket. LDS counting-sort by local key; emits CSR
// off[], sorted records, and (UI) dinv[].
// ---------------------------------------------------------------------------
__global__ __launch_bounds__(256) void bucket_finalize(const int* __restrict__ boff_kg,
                                                       const int* __restrict__ boff_ui,
                                                       unsigned int* __restrict__ kgrec,
                                                       int* __restrict__ uirec,
                                                       int* __restrict__ off_kg,
                                                       int* __restrict__ off_ui,
                                                       float* __restrict__ dinv,
                                                       int e_kg, int e_ui) {
    __shared__ unsigned int rec[CAPD];
    __shared__ int hist[512];
    bool iskg = blockIdx.x < NB_KG;
    int  b    = iskg ? blockIdx.x : blockIdx.x - NB_KG;
    const int* boff = iskg ? boff_kg : boff_ui;
    int ebeg = boff[b], eend = boff[b + 1];
    int ne   = min(eend - ebeg, CAPD);
    int key_base = iskg ? (b << 9) : (b << 8);
    int nkeys = iskg ? min(512, N_ENT - key_base) : min(256, N_NODES - key_base);
    int SH = iskg ? 23 : 18;
    int tid = threadIdx.x;

    for (int i = tid; i < ne; i += 256)
        rec[i] = iskg ? kgrec[ebeg + i] : (unsigned int)uirec[ebeg + i];
    for (int i = tid; i < 512; i += 256) hist[i] = 0;
    __syncthreads();
    for (int i = tid; i < ne; i += 256)
        atomicAdd(&hist[rec[i] >> SH], 1);
    __syncthreads();
    if (!iskg) {
        for (int i = tid; i < nkeys; i += 256) {
            int d = hist[i];
            dinv[key_base + i] = d > 0 ? 1.0f / sqrtf((float)d) : 0.0f;
        }
    }
    int i0 = tid, i1 = tid + 256;
    int v0 = hist[i0], v1 = hist[i1];
    __syncthreads();
    for (int o = 1; o < 512; o <<= 1) {
        int a0 = (i0 >= o) ? hist[i0 - o] : 0;
        int a1 = (i1 >= o) ? hist[i1 - o] : 0;
        __syncthreads();
        hist[i0] += a0; hist[i1] += a1;
        __syncthreads();
    }
    int e0 = hist[i0] - v0, e1 = hist[i1] - v1;
    __syncthreads();
    hist[i0] = e0; hist[i1] = e1;
    int* offg = iskg ? off_kg : off_ui;
    if (i0 < nkeys) offg[key_base + i0] = ebeg + e0;
    if (i1 < nkeys) offg[key_base + i1] = ebeg + e1;
    if (blockIdx.x == 0 && tid == 0) {
        off_kg[N_ENT]   = e_kg;
        off_ui[N_NODES] = e_ui;
    }
    __syncthreads();
    for (int i = tid; i < ne; i += 256) {
        unsigned int r = rec[i];
        int k = r >> SH;
        int slot = atomicAdd(&hist[k], 1);
        if (iskg) kgrec[ebeg + slot] = r & 0x7FFFFFu;
        else      uirec[ebeg + slot] = (int)(r & 0x3FFFFu);
    }
}

// ---------------------------------------------------------------------------
// kg_aggregate: one wave per entity row, 4x unrolled edge loop (R5 form —
// 8x was neutral-to-negative).
// ---------------------------------------------------------------------------
__global__ void kg_aggregate(const int* __restrict__ off, const unsigned int* __restrict__ packed,
                             const float* __restrict__ y, const float* __restrict__ x0,
                             const float* __restrict__ rel_emb, float* __restrict__ xkg,
                             int n_ent) {
    __shared__ float gate[N_REL * 64];
    for (int idx = threadIdx.x; idx < N_REL * 64; idx += blockDim.x)
        gate[idx] = 1.0f / (1.0f + __expf(-rel_emb[idx]));
    __syncthreads();
    int lane = threadIdx.x & 63;
    int wave = (blockIdx.x * blockDim.x + threadIdx.x) >> 6;
    int nw   = (gridDim.x * blockDim.x) >> 6;
    for (int r = wave; r < n_ent; r += nw) {
        int beg = off[r], end = off[r + 1];
        float acc0 = 0.f, acc1 = 0.f, acc2 = 0.f, acc3 = 0.f;
        int p = beg;
        for (; p + 4 <= end; p += 4) {
            unsigned int pk0 = packed[p + 0];
            unsigned int pk1 = packed[p + 1];
            unsigned int pk2 = packed[p + 2];
            unsigned int pk3 = packed[p + 3];
            float v0 = y[(long)(pk0 & 0x3FFFF) * 64 + lane];
            float v1 = y[(long)(pk1 & 0x3FFFF) * 64 + lane];
            float v2 = y[(long)(pk2 & 0x3FFFF) * 64 + lane];
            float v3 = y[(long)(pk3 & 0x3FFFF) * 64 + lane];
            acc0 += v0 * gate[(pk0 >> 18) * 64 + lane];
            acc1 += v1 * gate[(pk1 >> 18) * 64 + lane];
            acc2 += v2 * gate[(pk2 >> 18) * 64 + lane];
            acc3 += v3 * gate[(pk3 >> 18) * 64 + lane];
        }
        for (; p < end; p++) {
            unsigned int pk = packed[p];
            acc0 += y[(long)(pk & 0x3FFFF) * 64 + lane] * gate[(pk >> 18) * 64 + lane];
        }
        float acc = (acc0 + acc1) + (acc2 + acc3);
        float deg = fmaxf((float)(end - beg), 1.0f);
        float v = acc / deg + x0[(long)r * 64 + lane];
        v = (v > 0.0f) ? v : (__expf(v) - 1.0f);      // elu, alpha=1
        float ss = v * v;
        #pragma unroll
        for (int o = 32; o; o >>= 1) ss += __shfl_xor(ss, o);
        xkg[(long)r * 64 + lane] = v / fmaxf(sqrtf(ss), 1e-12f);
    }
}

// ---------------------------------------------------------------------------
// build_all: all_emb = [user_emb ; xkg[i2e]]
// ---------------------------------------------------------------------------
__global__ void build_all(const float* __restrict__ user_emb, const float* __restrict__ xkg,
                          const int* __restrict__ i2e, float* __restrict__ all_emb) {
    int lane = threadIdx.x & 63;
    int wave = (blockIdx.x * blockDim.x + threadIdx.x) >> 6;
    int nw   = (gridDim.x * blockDim.x) >> 6;
    for (int r = wave; r < N_NODES; r += nw) {
        float v;
        if (r < N_USERS) {
            v = user_emb[(long)r * 64 + lane];
        } else {
            long ent = i2e[r - N_USERS];
            v = xkg[ent * 64 + lane];
        }
        all_emb[(long)r * 64 + lane] = v;
    }
}

// ---------------------------------------------------------------------------
// ui_aggregate: val = dinv[r]*dinv[c]; 4x unrolled gather loop (R5 form).
// final = 0.5*(all_emb[r] + dinv[r]*sum(dinv[c]*all_emb[c]))
// ---------------------------------------------------------------------------
__global__ void ui_aggregate(const int* __restrict__ off, const int* __restrict__ colrec,
                             const float* __restrict__ all_emb, const float* __restrict__ dinv,
                             float* __restrict__ final_emb) {
    int lane = threadIdx.x & 63;
    int wave = (blockIdx.x * blockDim.x + threadIdx.x) >> 6;
    int nw   = (gridDim.x * blockDim.x) >> 6;
    for (int r = wave; r < N_NODES; r += nw) {
        int beg = off[r], end = off[r + 1];
        float acc0 = 0.f, acc1 = 0.f, acc2 = 0.f, acc3 = 0.f;
        int p = beg;
        for (; p + 4 <= end; p += 4) {
            int c0 = colrec[p + 0];
            int c1 = colrec[p + 1];
            int c2 = colrec[p + 2];
            int c3 = colrec[p + 3];
            acc0 += dinv[c0] * all_emb[(long)c0 * 64 + lane];
            acc1 += dinv[c1] * all_emb[(long)c1 * 64 + lane];
            acc2 += dinv[c2] * all_emb[(long)c2 * 64 + lane];
            acc3 += dinv[c3] * all_emb[(long)c3 * 64 + lane];
        }
        for (; p < end; p++) {
            int c = colrec[p];
            acc0 += dinv[c] * all_emb[(long)c * 64 + lane];
        }
        float acc = ((acc0 + acc1) + (acc2 + acc3)) * dinv[r];
        final_emb[(long)r * 64 + lane] =
            0.5f * (all_emb[(long)r * 64 + lane] + acc);
    }
}

// ---------------------------------------------------------------------------
// Epilogue (intent folded in): one wave per sample.
// ---------------------------------------------------------------------------
__global__ void final_kernel(const int* __restrict__ u, const int* __restrict__ ipos,
                             const int* __restrict__ ineg,
                             const float* __restrict__ final_emb,
                             const float* __restrict__ all_emb,
                             const float* __restrict__ rw, const float* __restrict__ rb,
                             const float* __restrict__ iw, const float* __restrict__ rel_emb,
                             float* __restrict__ out, int B) {
    __shared__ float sh_intent[128];
    if (threadIdx.x < 64) {
        int j = threadIdx.x;
        for (int k = 0; k < 2; k++) {
            float m = -1e30f;
            for (int r = 0; r < N_REL; r++) m = fmaxf(m, iw[k * N_REL + r]);
            float Z = 0.f, acc = 0.f;
            for (int r = 0; r < N_REL; r++) {
                float e = __expf(iw[k * N_REL + r] - m);
                Z += e;
                acc += e * rel_emb[r * 64 + j];
            }
            sh_intent[k * 64 + j] = acc / Z;
        }
    }
    __syncthreads();
    int lane = threadIdx.x & 63;
    int wave = (blockIdx.x * blockDim.x + threadIdx.x) >> 6;
    int nw   = (gridDim.x * blockDim.x) >> 6;
    for (int b = wave; b < B; b += nw) {
        int uu = u[b];
        float up = final_emb[(long)uu * 64 + lane];
        float l0 = up * rw[lane];
        float l1 = up * rw[64 + lane];
        #pragma unroll
        for (int o = 32; o; o >>= 1) {
            l0 += __shfl_xor(l0, o);
            l1 += __shfl_xor(l1, o);
        }
        l0 += rb[0]; l1 += rb[1];
        float m  = fmaxf(l0, l1);
        float e0 = __expf(l0 - m), e1 = __expf(l1 - m);
        float inv = 1.0f / (e0 + e1);
        float p0 = e0 * inv, p1 = e1 * inv;
        float ue = up + p0 * sh_intent[lane] + p1 * sh_intent[64 + lane];

        int it = ipos[b];
        long rr = (long)(N_USERS + it) * 64 + lane;
        float ie = final_emb[rr] + all_emb[rr];
        float dp = ue * ie;
        #pragma unroll
        for (int o = 32; o; o >>= 1) dp += __shfl_xor(dp, o);
        if (lane == 0) out[b] = dp;

        it = ineg[b];
        rr = (long)(N_USERS + it) * 64 + lane;
        ie = final_emb[rr] + all_emb[rr];
        dp = ue * ie;
        #pragma unroll
        for (int o = 32; o; o >>= 1) dp += __shfl_xor(dp, o);
        if (lane == 0) out[B + b] = dp;
    }
}

extern "C" void kernel_launch(void* const* d_in, const int* in_sizes, int n_in,
                              void* d_out, int out_size, void* d_ws, size_t ws_size,
                              hipStream_t stream) {
    const int*   u          = (const int*)  d_in[0];
    const int*   ipos       = (const int*)  d_in[1];
    const int*   ineg       = (const int*)  d_in[2];
    const float* user_emb   = (const float*)d_in[3];
    const float* entity_emb = (const float*)d_in[4];
    const float* rel_emb    = (const float*)d_in[5];
    const float* iw         = (const float*)d_in[6];
    const float* rw         = (const float*)d_in[7];
    const float* rb         = (const float*)d_in[8];
    const float* kgw        = (const float*)d_in[9];
    const int*   i2e        = (const int*)  d_in[11];
    const int*   kg_src     = (const int*)  d_in[12];
    const int*   kg_dst     = (const int*)  d_in[13];
    const int*   kg_rel     = (const int*)  d_in[14];
    const int*   ui_row     = (const int*)  d_in[15];
    const int*   ui_col     = (const int*)  d_in[16];
    float*       out        = (float*)d_out;

    int B    = in_sizes[0];
    int e_kg = in_sizes[12];
    int e_ui = in_sizes[15];

    // ---------------- workspace layout (bytes) ----------------
    char* ws = (char*)d_ws;
    float*        y          = (float*)(ws + 0);            // 51.2 MB, reused as all_emb
    float*        all_emb    = (float*)(ws + 0);
    float*        xkg        = (float*)(ws + 51200000);     // 51.2 MB, reused as final_emb
    float*        final_emb  = (float*)(ws + 51200000);
    unsigned int* kgrec      = (unsigned int*)(ws + 102400000); // 8 MB (2M recs)
    int*          uirec      = (int*)(ws + 110400000);      // 8 MB (2M recs)
    int*          off_kg     = (int*)(ws + 118400000);      // 200001 ints
    int*          off_ui     = (int*)(ws + 119200256);      // 150001 ints
    float*        dinv       = (float*)(ws + 119800512);    // 150000 floats
    int*          bcnt       = (int*)(ws + 120400512);      // 977 ints
    int*          boff_kg    = (int*)(ws + 120404480);      // 392 ints
    int*          boff_ui    = (int*)(ws + 120406272);      // 587 ints
    int*          bcur       = (int*)(ws + 120408704);      // 977 ints

    hipMemsetAsync(bcnt, 0, NB_TOT * sizeof(int), stream);
    bucket_hist    <<<256, 256, 0, stream>>>(kg_dst, ui_row, bcnt, e_kg, e_ui);
    bucket_scan    <<<1,   256, 0, stream>>>(bcnt, boff_kg, boff_ui, bcur, e_kg, e_ui);
    bucket_scatter <<<512, 256, 0, stream>>>(kg_src, kg_dst, kg_rel, ui_row, ui_col,
                                             bcur, kgrec, uirec, e_kg, e_ui);
    bucket_finalize<<<NB_TOT, 256, 0, stream>>>(boff_kg, boff_ui, kgrec, uirec,
                                                off_kg, off_ui, dinv, e_kg, e_ui);

    ent_matmul  <<<(N_ENT + 127) / 128, 128, 0, stream>>>(entity_emb, kgw, y, N_ENT);
    kg_aggregate<<<4096, 256, 0, stream>>>(off_kg, kgrec, y, entity_emb, rel_emb, xkg, N_ENT);
    build_all   <<<2048, 256, 0, stream>>>(user_emb, xkg, i2e, all_emb);
    ui_aggregate<<<4096, 256, 0, stream>>>(off_ui, uirec, all_emb, dinv, final_emb);
    final_kernel<<<256,  256, 0, stream>>>(u, ipos, ineg, final_emb, all_emb,
                                           rw, rb, iw, rel_emb, out, B);
}

// Round 8
// 515.212 us; speedup vs baseline: 1.6059x; 1.0379x over previous
//
#include <hip/hip_runtime.h>
#include <math.h>

#define N_USERS 50000
#define N_ITEMS 100000
#define N_ENT   200000
#define N_NODES (N_USERS + N_ITEMS)
#define N_REL   32
#define DIM     64

#define NB_KG  391          // KG buckets: dst>>9 (512 keys each)
#define NB_UI  586          // UI buckets: row>>8 (256 keys each)
#define NB_TOT (NB_KG + NB_UI)   // 977
#define CAPD   8192         // max edges per bucket in finalize LDS

__device__ __forceinline__ unsigned short f2bf(float f) {   // RNE f32->bf16
    unsigned u = __float_as_uint(f);
    u += 0x7FFFu + ((u >> 16) & 1u);
    return (unsigned short)(u >> 16);
}
__device__ __forceinline__ float bf2f(unsigned short h) {
    return __uint_as_float((unsigned)h << 16);
}

// ---------------------------------------------------------------------------
// ent_matmul: y16 = bf16(x @ W^T), register-tiled LDS GEMM.
// 128 rows/block, 128 threads, 8x8 C-tile per thread. (No shuffles: CDNA
// __shfl = ds_bpermute -> LDS-pipe bound, R6 lesson.)
// ---------------------------------------------------------------------------
__global__ __launch_bounds__(128) void ent_matmul(const float* __restrict__ x,
                                                  const float* __restrict__ w,
                                                  unsigned short* __restrict__ y16,
                                                  int n_ent) {
    __shared__ float xt[64][132];
    __shared__ float wt[64][68];
    int tid  = threadIdx.x;
    int base = blockIdx.x * 128;

    #pragma unroll
    for (int q = 0; q < 8; q++) {
        int idx = q * 128 + tid;
        int j = idx >> 4, k4 = idx & 15;
        float4 v = ((const float4*)w)[idx];
        wt[4 * k4 + 0][j] = v.x;
        wt[4 * k4 + 1][j] = v.y;
        wt[4 * k4 + 2][j] = v.z;
        wt[4 * k4 + 3][j] = v.w;
    }
    #pragma unroll
    for (int q = 0; q < 16; q++) {
        int idx = q * 128 + tid;
        int r = idx >> 4, k4 = idx & 15;
        int gr = base + r;
        if (gr < n_ent) {
            float4 v = ((const float4*)x)[(long)gr * 16 + k4];
            xt[4 * k4 + 0][r] = v.x;
            xt[4 * k4 + 1][r] = v.y;
            xt[4 * k4 + 2][r] = v.z;
            xt[4 * k4 + 3][r] = v.w;
        }
    }
    __syncthreads();

    int j0 = (tid & 7) * 8;
    int r0 = (tid >> 3) * 8;
    float acc[8][8];
    #pragma unroll
    for (int i = 0; i < 8; i++)
        #pragma unroll
        for (int j = 0; j < 8; j++) acc[i][j] = 0.f;

    #pragma unroll 4
    for (int k = 0; k < 64; k++) {
        float4 xa = *(const float4*)&xt[k][r0];
        float4 xb = *(const float4*)&xt[k][r0 + 4];
        float4 wa = *(const float4*)&wt[k][j0];
        float4 wb = *(const float4*)&wt[k][j0 + 4];
        float xr[8] = {xa.x, xa.y, xa.z, xa.w, xb.x, xb.y, xb.z, xb.w};
        float wr[8] = {wa.x, wa.y, wa.z, wa.w, wb.x, wb.y, wb.z, wb.w};
        #pragma unroll
        for (int i = 0; i < 8; i++)
            #pragma unroll
            for (int j = 0; j < 8; j++)
                acc[i][j] += xr[i] * wr[j];
    }

    #pragma unroll
    for (int i = 0; i < 8; i++) {
        int gr = base + r0 + i;
        if (gr < n_ent) {
            uint4 o;
            o.x = (unsigned)f2bf(acc[i][0]) | ((unsigned)f2bf(acc[i][1]) << 16);
            o.y = (unsigned)f2bf(acc[i][2]) | ((unsigned)f2bf(acc[i][3]) << 16);
            o.z = (unsigned)f2bf(acc[i][4]) | ((unsigned)f2bf(acc[i][5]) << 16);
            o.w = (unsigned)f2bf(acc[i][6]) | ((unsigned)f2bf(acc[i][7]) << 16);
            *(uint4*)&y16[(long)gr * 64 + j0] = o;
        }
    }
}

// ---------------------------------------------------------------------------
// Pass A: per-block LDS bucket histogram
// ---------------------------------------------------------------------------
__global__ __launch_bounds__(256) void bucket_hist(const int* __restrict__ kg_dst,
                                                   const int* __restrict__ ui_row,
                                                   int* __restrict__ bcnt,
                                                   int e_kg, int e_ui) {
    __shared__ int h[NB_TOT];
    for (int i = threadIdx.x; i < NB_TOT; i += 256) h[i] = 0;
    __syncthreads();
    int n = e_kg + e_ui;
    int t = blockIdx.x * 256 + threadIdx.x;
    int stride = gridDim.x * 256;
    for (int e = t; e < n; e += stride) {
        int bk = (e < e_kg) ? (kg_dst[e] >> 9) : (NB_KG + (ui_row[e - e_kg] >> 8));
        atomicAdd(&h[bk], 1);
    }
    __syncthreads();
    for (int i = threadIdx.x; i < NB_TOT; i += 256)
        if (h[i]) atomicAdd(&bcnt[i], h[i]);
}

// ---------------------------------------------------------------------------
// Pass B: exclusive scan of bucket counts
// ---------------------------------------------------------------------------
__global__ __launch_bounds__(256) void bucket_scan(const int* __restrict__ bcnt,
                                                   int* __restrict__ boff_kg,
                                                   int* __restrict__ boff_ui,
                                                   int* __restrict__ bcur,
                                                   int e_kg, int e_ui) {
    __shared__ int sh[1024];
    int t = threadIdx.x;
    for (int seg = 0; seg < 2; seg++) {
        int NB = seg ? NB_UI : NB_KG;
        const int* src = bcnt + (seg ? NB_KG : 0);
        int idx[4] = { t, t + 256, t + 512, t + 768 };
        int v[4];
        #pragma unroll
        for (int q = 0; q < 4; q++) {
            v[q] = (idx[q] < NB) ? src[idx[q]] : 0;
            sh[idx[q]] = v[q];
        }
        __syncthreads();
        for (int o = 1; o < 1024; o <<= 1) {
            int a[4];
            #pragma unroll
            for (int q = 0; q < 4; q++) a[q] = (idx[q] >= o) ? sh[idx[q] - o] : 0;
            __syncthreads();
            #pragma unroll
            for (int q = 0; q < 4; q++) sh[idx[q]] += a[q];
            __syncthreads();
        }
        int* boff = seg ? boff_ui : boff_kg;
        int  base = seg ? NB_KG : 0;
        #pragma unroll
        for (int q = 0; q < 4; q++) {
            if (idx[q] < NB) {
                int ex = sh[idx[q]] - v[q];
                boff[idx[q]] = ex;
                bcur[base + idx[q]] = ex;
            }
        }
        if (t == 0) boff[NB] = seg ? e_ui : e_kg;
        __syncthreads();
    }
}

// ---------------------------------------------------------------------------
// Pass C: scatter edges into bucket regions.
// KG rec: src(18) | rel<<18 (5) | dst_local<<23 (9)
// UI rec: col(18) | row_local<<18 (8)
// ---------------------------------------------------------------------------
__global__ __launch_bounds__(256) void bucket_scatter(const int* __restrict__ kg_src,
                                                      const int* __restrict__ kg_dst,
                                                      const int* __restrict__ kg_rel,
                                                      const int* __restrict__ ui_row,
                                                      const int* __restrict__ ui_col,
                                                      int* __restrict__ bcur,
                                                      unsigned int* __restrict__ kgrec,
                                                      int* __restrict__ uirec,
                                                      int e_kg, int e_ui) {
    __shared__ int h[NB_TOT];
    __shared__ int lbase[NB_TOT];
    int n = e_kg + e_ui;
    int nchunks = (n + 4095) >> 12;
    int tid = threadIdx.x;
    for (int c = blockIdx.x; c < nchunks; c += gridDim.x) {
        int base = c << 12;
        for (int i = tid; i < NB_TOT; i += 256) h[i] = 0;
        __syncthreads();
        unsigned int rec[16];
        int bk[16];
        #pragma unroll
        for (int j = 0; j < 16; j++) {
            int e = base + j * 256 + tid;
            if (e < n) {
                if (e < e_kg) {
                    int d = kg_dst[e];
                    bk[j]  = d >> 9;
                    rec[j] = (unsigned int)kg_src[e] | ((unsigned int)kg_rel[e] << 18)
                             | ((unsigned int)(d & 511) << 23);
                } else {
                    int i2 = e - e_kg;
                    int r  = ui_row[i2];
                    bk[j]  = NB_KG + (r >> 8);
                    rec[j] = (unsigned int)ui_col[i2] | ((unsigned int)(r & 255) << 18);
                }
                atomicAdd(&h[bk[j]], 1);
            } else bk[j] = -1;
        }
        __syncthreads();
        for (int i = tid; i < NB_TOT; i += 256) {
            int cc = h[i];
            lbase[i] = cc ? atomicAdd(&bcur[i], cc) : 0;
        }
        __syncthreads();
        #pragma unroll
        for (int j = 0; j < 16; j++) {
            if (bk[j] >= 0) {
                int pos = atomicAdd(&lbase[bk[j]], 1);
                if (bk[j] < NB_KG) kgrec[pos] = rec[j];
                else               uirec[pos] = (int)rec[j];
            }
        }
        __syncthreads();
    }
}

// ---------------------------------------------------------------------------
// Pass D: one block per bucket. LDS counting-sort by local key; emits CSR
// off[], sorted records, and (UI) dinv[].
// ---------------------------------------------------------------------------
__global__ __launch_bounds__(256) void bucket_finalize(const int* __restrict__ boff_kg,
                                                       const int* __restrict__ boff_ui,
                                                       unsigned int* __restrict__ kgrec,
                                                       int* __restrict__ uirec,
                                                       int* __restrict__ off_kg,
                                                       int* __restrict__ off_ui,
                                                       float* __restrict__ dinv,
                                                       int e_kg, int e_ui) {
    __shared__ unsigned int rec[CAPD];
    __shared__ int hist[512];
    bool iskg = blockIdx.x < NB_KG;
    int  b    = iskg ? blockIdx.x : blockIdx.x - NB_KG;
    const int* boff = iskg ? boff_kg : boff_ui;
    int ebeg = boff[b], eend = boff[b + 1];
    int ne   = min(eend - ebeg, CAPD);
    int key_base = iskg ? (b << 9) : (b << 8);
    int nkeys = iskg ? min(512, N_ENT - key_base) : min(256, N_NODES - key_base);
    int SH = iskg ? 23 : 18;
    int tid = threadIdx.x;

    for (int i = tid; i < ne; i += 256)
        rec[i] = iskg ? kgrec[ebeg + i] : (unsigned int)uirec[ebeg + i];
    for (int i = tid; i < 512; i += 256) hist[i] = 0;
    __syncthreads();
    for (int i = tid; i < ne; i += 256)
        atomicAdd(&hist[rec[i] >> SH], 1);
    __syncthreads();
    if (!iskg) {
        for (int i = tid; i < nkeys; i += 256) {
            int d = hist[i];
            dinv[key_base + i] = d > 0 ? 1.0f / sqrtf((float)d) : 0.0f;
        }
    }
    int i0 = tid, i1 = tid + 256;
    int v0 = hist[i0], v1 = hist[i1];
    __syncthreads();
    for (int o = 1; o < 512; o <<= 1) {
        int a0 = (i0 >= o) ? hist[i0 - o] : 0;
        int a1 = (i1 >= o) ? hist[i1 - o] : 0;
        __syncthreads();
        hist[i0] += a0; hist[i1] += a1;
        __syncthreads();
    }
    int e0 = hist[i0] - v0, e1 = hist[i1] - v1;
    __syncthreads();
    hist[i0] = e0; hist[i1] = e1;
    int* offg = iskg ? off_kg : off_ui;
    if (i0 < nkeys) offg[key_base + i0] = ebeg + e0;
    if (i1 < nkeys) offg[key_base + i1] = ebeg + e1;
    if (blockIdx.x == 0 && tid == 0) {
        off_kg[N_ENT]   = e_kg;
        off_ui[N_NODES] = e_ui;
    }
    __syncthreads();
    for (int i = tid; i < ne; i += 256) {
        unsigned int r = rec[i];
        int k = r >> SH;
        int slot = atomicAdd(&hist[k], 1);
        if (iskg) kgrec[ebeg + slot] = r & 0x7FFFFFu;
        else      uirec[ebeg + slot] = (int)(r & 0x3FFFFu);
    }
}

// ---------------------------------------------------------------------------
// kg_aggregate: one wave per entity row, 4x unrolled; gathers bf16 y rows.
// ---------------------------------------------------------------------------
__global__ void kg_aggregate(const int* __restrict__ off,
                             const unsigned int* __restrict__ packed,
                             const unsigned short* __restrict__ y16,
                             const float* __restrict__ x0,
                             const float* __restrict__ rel_emb,
                             float* __restrict__ xkg, int n_ent) {
    __shared__ float gate[N_REL * 64];
    for (int idx = threadIdx.x; idx < N_REL * 64; idx += blockDim.x)
        gate[idx] = 1.0f / (1.0f + __expf(-rel_emb[idx]));
    __syncthreads();
    int lane = threadIdx.x & 63;
    int wave = (blockIdx.x * blockDim.x + threadIdx.x) >> 6;
    int nw   = (gridDim.x * blockDim.x) >> 6;
    for (int r = wave; r < n_ent; r += nw) {
        int beg = off[r], end = off[r + 1];
        float acc0 = 0.f, acc1 = 0.f, acc2 = 0.f, acc3 = 0.f;
        int p = beg;
        for (; p + 4 <= end; p += 4) {
            unsigned int pk0 = packed[p + 0];
            unsigned int pk1 = packed[p + 1];
            unsigned int pk2 = packed[p + 2];
            unsigned int pk3 = packed[p + 3];
            float v0 = bf2f(y16[(long)(pk0 & 0x3FFFF) * 64 + lane]);
            float v1 = bf2f(y16[(long)(pk1 & 0x3FFFF) * 64 + lane]);
            float v2 = bf2f(y16[(long)(pk2 & 0x3FFFF) * 64 + lane]);
            float v3 = bf2f(y16[(long)(pk3 & 0x3FFFF) * 64 + lane]);
            acc0 += v0 * gate[(pk0 >> 18) * 64 + lane];
            acc1 += v1 * gate[(pk1 >> 18) * 64 + lane];
            acc2 += v2 * gate[(pk2 >> 18) * 64 + lane];
            acc3 += v3 * gate[(pk3 >> 18) * 64 + lane];
        }
        for (; p < end; p++) {
            unsigned int pk = packed[p];
            acc0 += bf2f(y16[(long)(pk & 0x3FFFF) * 64 + lane]) * gate[(pk >> 18) * 64 + lane];
        }
        float acc = (acc0 + acc1) + (acc2 + acc3);
        float deg = fmaxf((float)(end - beg), 1.0f);
        float v = acc / deg + x0[(long)r * 64 + lane];
        v = (v > 0.0f) ? v : (__expf(v) - 1.0f);      // elu, alpha=1
        float ss = v * v;
        #pragma unroll
        for (int o = 32; o; o >>= 1) ss += __shfl_xor(ss, o);
        xkg[(long)r * 64 + lane] = v / fmaxf(sqrtf(ss), 1e-12f);
    }
}

// ---------------------------------------------------------------------------
// build_all: all_emb = [user_emb ; xkg[i2e]] (f32) + bf16 gather copy all16
// ---------------------------------------------------------------------------
__global__ void build_all(const float* __restrict__ user_emb, const float* __restrict__ xkg,
                          const int* __restrict__ i2e, float* __restrict__ all_emb,
                          unsigned short* __restrict__ all16) {
    int lane = threadIdx.x & 63;
    int wave = (blockIdx.x * blockDim.x + threadIdx.x) >> 6;
    int nw   = (gridDim.x * blockDim.x) >> 6;
    for (int r = wave; r < N_NODES; r += nw) {
        float v;
        if (r < N_USERS) {
            v = user_emb[(long)r * 64 + lane];
        } else {
            long ent = i2e[r - N_USERS];
            v = xkg[ent * 64 + lane];
        }
        all_emb[(long)r * 64 + lane] = v;
        all16[(long)r * 64 + lane]   = f2bf(v);
    }
}

// ---------------------------------------------------------------------------
// ui_aggregate: val = dinv[r]*dinv[c]; gathers bf16 all16 rows.
// final = 0.5*(all_emb[r] + dinv[r]*sum(dinv[c]*all16[c]))
// ---------------------------------------------------------------------------
__global__ void ui_aggregate(const int* __restrict__ off, const int* __restrict__ colrec,
                             const float* __restrict__ all_emb,
                             const unsigned short* __restrict__ all16,
                             const float* __restrict__ dinv,
                             float* __restrict__ final_emb) {
    int lane = threadIdx.x & 63;
    int wave = (blockIdx.x * blockDim.x + threadIdx.x) >> 6;
    int nw   = (gridDim.x * blockDim.x) >> 6;
    for (int r = wave; r < N_NODES; r += nw) {
        int beg = off[r], end = off[r + 1];
        float acc0 = 0.f, acc1 = 0.f, acc2 = 0.f, acc3 = 0.f;
        int p = beg;
        for (; p + 4 <= end; p += 4) {
            int c0 = colrec[p + 0];
            int c1 = colrec[p + 1];
            int c2 = colrec[p + 2];
            int c3 = colrec[p + 3];
            acc0 += dinv[c0] * bf2f(all16[(long)c0 * 64 + lane]);
            acc1 += dinv[c1] * bf2f(all16[(long)c1 * 64 + lane]);
            acc2 += dinv[c2] * bf2f(all16[(long)c2 * 64 + lane]);
            acc3 += dinv[c3] * bf2f(all16[(long)c3 * 64 + lane]);
        }
        for (; p < end; p++) {
            int c = colrec[p];
            acc0 += dinv[c] * bf2f(all16[(long)c * 64 + lane]);
        }
        float acc = ((acc0 + acc1) + (acc2 + acc3)) * dinv[r];
        final_emb[(long)r * 64 + lane] =
            0.5f * (all_emb[(long)r * 64 + lane] + acc);
    }
}

// ---------------------------------------------------------------------------
// Epilogue (intent folded in): one wave per sample.
// ---------------------------------------------------------------------------
__global__ void final_kernel(const int* __restrict__ u, const int* __restrict__ ipos,
                             const int* __restrict__ ineg,
                             const float* __restrict__ final_emb,
                             const float* __restrict__ all_emb,
                             const float* __restrict__ rw, const float* __restrict__ rb,
                             const float* __restrict__ iw, const float* __restrict__ rel_emb,
                             float* __restrict__ out, int B) {
    __shared__ float sh_intent[128];
    if (threadIdx.x < 64) {
        int j = threadIdx.x;
        for (int k = 0; k < 2; k++) {
            float m = -1e30f;
            for (int r = 0; r < N_REL; r++) m = fmaxf(m, iw[k * N_REL + r]);
            float Z = 0.f, acc = 0.f;
            for (int r = 0; r < N_REL; r++) {
                float e = __expf(iw[k * N_REL + r] - m);
                Z += e;
                acc += e * rel_emb[r * 64 + j];
            }
            sh_intent[k * 64 + j] = acc / Z;
        }
    }
    __syncthreads();
    int lane = threadIdx.x & 63;
    int wave = (blockIdx.x * blockDim.x + threadIdx.x) >> 6;
    int nw   = (gridDim.x * blockDim.x) >> 6;
    for (int b = wave; b < B; b += nw) {
        int uu = u[b];
        float up = final_emb[(long)uu * 64 + lane];
        float l0 = up * rw[lane];
        float l1 = up * rw[64 + lane];
        #pragma unroll
        for (int o = 32; o; o >>= 1) {
            l0 += __shfl_xor(l0, o);
            l1 += __shfl_xor(l1, o);
        }
        l0 += rb[0]; l1 += rb[1];
        float m  = fmaxf(l0, l1);
        float e0 = __expf(l0 - m), e1 = __expf(l1 - m);
        float inv = 1.0f / (e0 + e1);
        float p0 = e0 * inv, p1 = e1 * inv;
        float ue = up + p0 * sh_intent[lane] + p1 * sh_intent[64 + lane];

        int it = ipos[b];
        long rr = (long)(N_USERS + it) * 64 + lane;
        float ie = final_emb[rr] + all_emb[rr];
        float dp = ue * ie;
        #pragma unroll
        for (int o = 32; o; o >>= 1) dp += __shfl_xor(dp, o);
        if (lane == 0) out[b] = dp;

        it = ineg[b];
        rr = (long)(N_USERS + it) * 64 + lane;
        ie = final_emb[rr] + all_emb[rr];
        dp = ue * ie;
        #pragma unroll
        for (int o = 32; o; o >>= 1) dp += __shfl_xor(dp, o);
        if (lane == 0) out[B + b] = dp;
    }
}

extern "C" void kernel_launch(void* const* d_in, const int* in_sizes, int n_in,
                              void* d_out, int out_size, void* d_ws, size_t ws_size,
                              hipStream_t stream) {
    const int*   u          = (const int*)  d_in[0];
    const int*   ipos       = (const int*)  d_in[1];
    const int*   ineg       = (const int*)  d_in[2];
    const float* user_emb   = (const float*)d_in[3];
    const float* entity_emb = (const float*)d_in[4];
    const float* rel_emb    = (const float*)d_in[5];
    const float* iw         = (const float*)d_in[6];
    const float* rw         = (const float*)d_in[7];
    const float* rb         = (const float*)d_in[8];
    const float* kgw        = (const float*)d_in[9];
    const int*   i2e        = (const int*)  d_in[11];
    const int*   kg_src     = (const int*)  d_in[12];
    const int*   kg_dst     = (const int*)  d_in[13];
    const int*   kg_rel     = (const int*)  d_in[14];
    const int*   ui_row     = (const int*)  d_in[15];
    const int*   ui_col     = (const int*)  d_in[16];
    float*       out        = (float*)d_out;

    int B    = in_sizes[0];
    int e_kg = in_sizes[12];
    int e_ui = in_sizes[15];

    // ---------------- workspace layout (bytes) ----------------
    // y16 (bf16, 25.6 MB) dead after kg_aggregate -> all_emb (f32, 38.4 MB)
    // aliases offset 0. xkg (f32, 51.2 MB) dead after build_all -> final_emb
    // (f32, 38.4 MB) aliases it.
    char* ws = (char*)d_ws;
    unsigned short* y16       = (unsigned short*)(ws + 0);   // 25.6 MB
    float*          all_emb   = (float*)(ws + 0);            // 38.4 MB (after kg_agg)
    float*          xkg       = (float*)(ws + 38400000);     // 51.2 MB
    float*          final_emb = (float*)(ws + 38400000);     // 38.4 MB (after build_all)
    unsigned short* all16     = (unsigned short*)(ws + 89600000); // 19.2 MB
    unsigned int*   kgrec     = (unsigned int*)(ws + 108800000);  // 8 MB
    int*            uirec     = (int*)(ws + 116800000);      // 8 MB
    int*            off_kg    = (int*)(ws + 124800000);      // 200001 ints
    int*            off_ui    = (int*)(ws + 125600256);      // 150001 ints
    float*          dinv      = (float*)(ws + 126200512);    // 150000 floats
    int*            bcnt      = (int*)(ws + 126800512);      // 977 ints
    int*            boff_kg   = (int*)(ws + 126804480);      // 392 ints
    int*            boff_ui   = (int*)(ws + 126806272);      // 587 ints
    int*            bcur      = (int*)(ws + 126808704);      // 977 ints

    hipMemsetAsync(bcnt, 0, NB_TOT * sizeof(int), stream);
    bucket_hist    <<<256, 256, 0, stream>>>(kg_dst, ui_row, bcnt, e_kg, e_ui);
    bucket_scan    <<<1,   256, 0, stream>>>(bcnt, boff_kg, boff_ui, bcur, e_kg, e_ui);
    bucket_scatter <<<512, 256, 0, stream>>>(kg_src, kg_dst, kg_rel, ui_row, ui_col,
                                             bcur, kgrec, uirec, e_kg, e_ui);
    bucket_finalize<<<NB_TOT, 256, 0, stream>>>(boff_kg, boff_ui, kgrec, uirec,
                                                off_kg, off_ui, dinv, e_kg, e_ui);

    ent_matmul  <<<(N_ENT + 127) / 128, 128, 0, stream>>>(entity_emb, kgw, y16, N_ENT);
    kg_aggregate<<<4096, 256, 0, stream>>>(off_kg, kgrec, y16, entity_emb, rel_emb,
                                           xkg, N_ENT);
    build_all   <<<2048, 256, 0, stream>>>(user_emb, xkg, i2e, all_emb, all16);
    ui_aggregate<<<4096, 256, 0, stream>>>(off_ui, uirec, all_emb, all16, dinv, final_emb);
    final_kernel<<<256,  256, 0, stream>>>(u, ipos, ineg, final_emb, all_emb,
                                           rw, rb, iw, rel_emb, out, B);
}